// Round 12
// baseline (410.431 us; speedup 1.0000x reference)
//
#include <hip/hip_runtime.h>
#include <hip/hip_bf16.h>

// ---------------------------------------------------------------------------
// MessagePassing (e3nn scalar conv, 2 layers) on MI355X. Inputs f32, out f32.
// Round 12: (1) packed bf16 cvt via v_cvt_pk_bf16_f32 (guarded), (2) GEMM2
// loop interchange (B-frag loads 64->16), (3) npre fused into gpost (next
// layer's lin1 GEMM runs on the sin(out) still in registers/LDS).
// ---------------------------------------------------------------------------

namespace {
constexpr int NN = 50000;
constexpr int NE = 800000;
constexpr int SCAN_BLOCKS = 196;     // ceil(50000/256)

// ws layout (float indices)
constexpr long OFF_NF   = 0;         // f32 [1,600,000] inter-layer nf
constexpr long OFF_W0P  = 1600000;   // ushort[4096]
constexpr long OFF_W2P  = 1602048;   // ushort[16384]
constexpr long OFF_WNP  = 1610240;   // ushort[57344] node-GEMM B-frags
constexpr long OFF_OFF  = 1638912;   // int [50001]
constexpr long OFF_CUR  = 1688913;   // int [50000]
constexpr long OFF_PERM = 1738913;   // int [800000]
constexpr long OFF_BSUM = 2538913;   // int [256] block sums
constexpr long OFF_EF   = 2539172;   // ushort [25,600,000] (16-B aligned)
}

typedef __attribute__((ext_vector_type(8))) short short8;
typedef __attribute__((ext_vector_type(4))) float f32x4;
typedef unsigned int   __attribute__((may_alias)) u32a;
typedef unsigned short __attribute__((may_alias)) u16a;
typedef float          __attribute__((may_alias)) f32a;

__device__ __forceinline__ float us2f(unsigned int u) {
    unsigned int x = u << 16; float f;
    __builtin_memcpy(&f, &x, sizeof(f));
    return f;
}
__device__ __forceinline__ unsigned short f2us(float f) {
    __hip_bfloat16 h = __float2bfloat16(f);
    unsigned short s;
    __builtin_memcpy(&s, &h, sizeof(s));
    return s;
}

#if defined(__has_builtin)
#  if __has_builtin(__builtin_amdgcn_cvt_pk_bf16_f32)
#    define PKBF16 1
#  endif
#endif
// pack two f32 -> two bf16 in one u32 (lo = a, hi = b)
__device__ __forceinline__ unsigned int f2us2(float a, float b) {
#ifdef PKBF16
    auto r = __builtin_amdgcn_cvt_pk_bf16_f32(a, b);
    unsigned int u; __builtin_memcpy(&u, &r, 4);
    return u;
#else
    return (unsigned)f2us(a) | ((unsigned)f2us(b) << 16);
#endif
}
__device__ __forceinline__ short8 mk_frag(unsigned int u0, unsigned int u1,
                                          unsigned int u2, unsigned int u3) {
    unsigned int u[4] = {u0, u1, u2, u3};
    short8 a; __builtin_memcpy(&a, u, 16);
    return a;
}

// ------------- hist + all weight packing ------------------------------------
__global__ __launch_bounds__(256) void k_hist(
        const int* __restrict__ dst, int* __restrict__ cnt,
        const float* __restrict__ f0, const float* __restrict__ f1,
        const float* __restrict__ l1w, const float* __restrict__ scw,
        const float* __restrict__ l2w, const float* __restrict__ aw,
        unsigned short* __restrict__ w0p, unsigned short* __restrict__ w2p,
        unsigned short* __restrict__ wnp) {
    int i = blockIdx.x * 256 + threadIdx.x;
    if (i < NE) atomicAdd(&cnt[dst[i]], 1);
    if (i < 4096) {                     // w0p [l][nt4][lane][i8], 0.25 folded
        int l = i >> 11, r = i & 2047;
        int nt = r >> 9, lane = (r >> 3) & 63, ii = r & 7;
        int k = (lane >> 4) * 8 + ii;
        int j = nt * 16 + (lane & 15);
        float v = (k < 16) ? 0.25f * f0[l * 1024 + k * 64 + j] : 0.f;
        w0p[i] = f2us(v);
    }
    if (i < 16384) {                    // w2p [l][kt*2+nt][lane][i8]
        int l = i >> 13, r = i & 8191;
        int g = r >> 9;
        int kt = g >> 1, nt = g & 1;
        int lane = (r >> 3) & 63, ii = r & 7;
        int K = kt * 32 + (lane >> 4) * 8 + ii;
        int j = K >> 2, v = K & 3;
        int u = nt * 16 + (lane & 15);
        w2p[i] = f2us(f1[l * 8192 + j * 128 + u * 4 + v]);
    }
    if (i < 57344) {                    // wnp [l][tile7][kt8][lane][i8]
        int l = i / 28672, r = i % 28672;
        int tile = r >> 12;
        int r2 = r & 4095;
        int kt = r2 >> 9, lane = (r2 >> 3) & 63, ii = r2 & 7;
        int k = kt * 32 + (lane >> 4) * 8 + ii;   // K = u*8+v
        int u = k >> 3, v = k & 7;
        int col = lane & 15;
        int uvb = l * 8192 + (u * 8 + v) * 32;
        float val;
        if (tile < 2)      val = l1w[uvb + tile * 16 + col];
        else if (tile < 4) val = scw[uvb + (tile - 2) * 16 + col];
        else if (tile < 6) val = l2w[uvb + (tile - 4) * 16 + col];
        else               val = (col == 0) ? aw[l * 256 + u * 8 + v] : 0.f;
        wnp[i] = f2us(val);
    }
}

// ------------------------- 3-phase parallel scan ----------------------------
__global__ __launch_bounds__(256) void k_scan1(const int* __restrict__ cnt,
                                               int* __restrict__ bsum) {
    __shared__ int s[256];
    int t = threadIdx.x;
    int i = blockIdx.x * 256 + t;
    s[t] = (i < NN) ? cnt[i] : 0;
    __syncthreads();
    for (int d = 128; d > 0; d >>= 1) {
        if (t < d) s[t] += s[t + d];
        __syncthreads();
    }
    if (t == 0) bsum[blockIdx.x] = s[0];
}

__global__ __launch_bounds__(256) void k_scan2(int* __restrict__ bsum) {
    __shared__ int s[256];
    int t = threadIdx.x;
    int v = (t < SCAN_BLOCKS) ? bsum[t] : 0;
    s[t] = v; __syncthreads();
    for (int d = 1; d < 256; d <<= 1) {
        int x = (t >= d) ? s[t - d] : 0;
        __syncthreads();
        s[t] += x;
        __syncthreads();
    }
    if (t < SCAN_BLOCKS) bsum[t] = s[t] - v;   // exclusive
}

__global__ __launch_bounds__(256) void k_scan3(
        const int* __restrict__ cnt, const int* __restrict__ bsum,
        int* __restrict__ off, int* __restrict__ cur) {
    __shared__ int s[256];
    int t = threadIdx.x;
    int i = blockIdx.x * 256 + t;
    int v = (i < NN) ? cnt[i] : 0;
    s[t] = v; __syncthreads();
    for (int d = 1; d < 256; d <<= 1) {
        int x = (t >= d) ? s[t - d] : 0;
        __syncthreads();
        s[t] += x;
        __syncthreads();
    }
    int excl = s[t] - v + bsum[blockIdx.x];
    if (i < NN) { off[i] = excl; cur[i] = excl; }
    if (i == NN - 1) off[NN] = excl + v;       // == NE
}

__global__ void k_perm(const int* __restrict__ dst, int* __restrict__ cur,
                       int* __restrict__ perm) {
    int e = blockIdx.x * 256 + threadIdx.x;
    if (e >= NE) return;
    perm[e] = atomicAdd(&cur[dst[e]], 1);
}

// ---- staging helpers (nf/nattr tile -> LDS) --------------------------------
__device__ __forceinline__ void stage_xy(const float* __restrict__ nf,
                                         const float* __restrict__ nattr,
                                         long n0, int t, f32a* Xs, f32a* Ys) {
    {
        long e = n0 * 32 + t * 8;
        int n = t >> 2, u = (t & 3) * 8;
        f32a* d = &Xs[n * 33 + u];
        if (e + 8 <= (long)NN * 32) {
            const float4* p = (const float4*)(nf + e);
            float4 q0 = p[0], q1 = p[1];
            d[0]=q0.x; d[1]=q0.y; d[2]=q0.z; d[3]=q0.w;
            d[4]=q1.x; d[5]=q1.y; d[6]=q1.z; d[7]=q1.w;
        } else {
#pragma unroll
            for (int i = 0; i < 8; i++)
                d[i] = (e + i < (long)NN * 32) ? nf[e + i] : 0.f;
        }
    }
    if (t < 128) {
        long e = n0 * 8 + t * 4;
        int n = t >> 1, v = (t & 1) * 4;
        f32a* d = &Ys[n * 9 + v];
        if (e + 4 <= (long)NN * 8) {
            float4 q = *(const float4*)(nattr + e);
            d[0]=q.x; d[1]=q.y; d[2]=q.z; d[3]=q.w;
        } else {
#pragma unroll
            for (int i = 0; i < 4; i++)
                d[i] = (e + i < (long)NN * 8) ? nattr[e + i] : 0.f;
        }
    }
}

// ------------- node pre (MFMA): xl = lin1(nf, nattr), layer 0 only ----------
__global__ __launch_bounds__(256) void k_npre_m(
        const float* __restrict__ nf, const float* __restrict__ nattr,
        const unsigned short* __restrict__ wnp_l, float* __restrict__ xl) {
    __shared__ f32a Xs[64 * 33];
    __shared__ f32a Ys[64 * 9];
    const int t = threadIdx.x;
    const long n0 = (long)blockIdx.x * 64;
    stage_xy(nf, nattr, n0, t, Xs, Ys);
    __syncthreads();

    const int lane = t & 63, w = t >> 6;
    const int l15 = lane & 15, quad = lane >> 4;
    const int nb = w * 16;
    float y[8], xk[8];
#pragma unroll
    for (int v = 0; v < 8; v++) y[v] = Ys[(nb + l15) * 9 + v];
#pragma unroll
    for (int kt = 0; kt < 8; kt++) xk[kt] = Xs[(nb + l15) * 33 + kt * 4 + quad];

    f32x4 a0, a1;
    a0[0]=0.f;a0[1]=0.f;a0[2]=0.f;a0[3]=0.f;
    a1[0]=0.f;a1[1]=0.f;a1[2]=0.f;a1[3]=0.f;
#pragma unroll
    for (int kt = 0; kt < 8; kt++) {
        float xv = xk[kt];
        short8 a = mk_frag(f2us2(xv*y[0], xv*y[1]), f2us2(xv*y[2], xv*y[3]),
                           f2us2(xv*y[4], xv*y[5]), f2us2(xv*y[6], xv*y[7]));
        const short8 b0 = *(const short8*)(wnp_l + ((0 * 8 + kt) * 512) + lane * 8);
        const short8 b1 = *(const short8*)(wnp_l + ((1 * 8 + kt) * 512) + lane * 8);
        a0 = __builtin_amdgcn_mfma_f32_16x16x32_bf16(a, b0, a0, 0, 0, 0);
        a1 = __builtin_amdgcn_mfma_f32_16x16x32_bf16(a, b1, a1, 0, 0, 0);
    }
#pragma unroll
    for (int r = 0; r < 4; r++) {
        long n = n0 + nb + quad * 4 + r;
        if (n < NN) {
            xl[n * 32 + l15]      = a0[r] * 0.0625f;
            xl[n * 32 + 16 + l15] = a1[r] * 0.0625f;
        }
    }
}

// ------------- per-wave edge kernel (GEMM2 loops interchanged) --------------
__global__ __launch_bounds__(256) void k_edge_w(
        const float* __restrict__ esc, const int* __restrict__ srcp,
        const int* __restrict__ perm, const float* __restrict__ ea_in,
        float* __restrict__ ea_out, const float* __restrict__ xl,
        const unsigned short* __restrict__ w0p,
        const unsigned short* __restrict__ w2p,
        const float* __restrict__ sew, unsigned short* __restrict__ ef_bf) {
    __shared__ __align__(16) unsigned char SCR[4][8704];

    const int t = threadIdx.x;
    const int w = t >> 6, lane = t & 63;
    const int l15 = lane & 15, quad = lane >> 4;
    const long e0 = ((long)blockIdx.x * 4 + w) * 64;
    u16a* Hs = (u16a*)SCR[w];
    f32a* Ts = (f32a*)SCR[w];

    // ---- GEMM1: H = sin(ES @ 0.25*W0) ----
    short8 bw0[4];
#pragma unroll
    for (int nt = 0; nt < 4; nt++)
        bw0[nt] = *(const short8*)(w0p + (nt * 64 + lane) * 8);
#pragma unroll
    for (int mt = 0; mt < 4; mt++) {
        int row = mt * 16 + l15;
        short8 a;
#pragma unroll
        for (int i = 0; i < 8; i++) a[i] = 0;
        if (quad < 2) {
            const float4* ep = (const float4*)(esc + (e0 + row) * 16 + quad * 8);
            float4 p0 = ep[0], p1 = ep[1];
            a = mk_frag(f2us2(p0.x, p0.y), f2us2(p0.z, p0.w),
                        f2us2(p1.x, p1.y), f2us2(p1.z, p1.w));
        }
#pragma unroll
        for (int nt = 0; nt < 4; nt++) {
            f32x4 c; c[0]=0.f; c[1]=0.f; c[2]=0.f; c[3]=0.f;
            c = __builtin_amdgcn_mfma_f32_16x16x32_bf16(a, bw0[nt], c, 0, 0, 0);
#pragma unroll
            for (int r = 0; r < 4; r++) {
                int edge = mt * 16 + quad * 4 + r;
                int j = nt * 16 + l15;
                Hs[edge * 68 + j] = f2us(__sinf(c[r]));
            }
        }
    }
    __syncthreads();

    // ---- GEMM2: T = G @ W2 (kt outer: 16 B-loads total) ----
    f32x4 acc[4][2];
#pragma unroll
    for (int mt = 0; mt < 4; mt++)
#pragma unroll
        for (int nt = 0; nt < 2; nt++) {
            acc[mt][nt][0]=0.f; acc[mt][nt][1]=0.f;
            acc[mt][nt][2]=0.f; acc[mt][nt][3]=0.f;
        }
    float4 eaq_r[4];
#pragma unroll
    for (int mt = 0; mt < 4; mt++)
        eaq_r[mt] = ((const float4*)ea_in)[e0 + mt * 16 + l15];
#pragma unroll
    for (int kt = 0; kt < 8; kt++) {
        const short8 b0 = *(const short8*)(w2p + ((kt*2+0)*64 + lane) * 8);
        const short8 b1 = *(const short8*)(w2p + ((kt*2+1)*64 + lane) * 8);
#pragma unroll
        for (int mt = 0; mt < 4; mt++) {
            int row = mt * 16 + l15;
            unsigned int hp = *(const u32a*)(Hs + row * 68 + kt * 8 + quad * 2);
            float H0 = us2f(hp & 0xFFFFu), H1 = us2f(hp >> 16);
            float4 ea = eaq_r[mt];
            short8 a = mk_frag(f2us2(H0*ea.x, H0*ea.y), f2us2(H0*ea.z, H0*ea.w),
                               f2us2(H1*ea.x, H1*ea.y), f2us2(H1*ea.z, H1*ea.w));
            acc[mt][0] = __builtin_amdgcn_mfma_f32_16x16x32_bf16(a, b0, acc[mt][0], 0, 0, 0);
            acc[mt][1] = __builtin_amdgcn_mfma_f32_16x16x32_bf16(a, b1, acc[mt][1], 0, 0, 0);
        }
    }
    __syncthreads();
#pragma unroll
    for (int mt = 0; mt < 4; mt++)
#pragma unroll
        for (int nt = 0; nt < 2; nt++)
#pragma unroll
            for (int r = 0; r < 4; r++)
                Ts[(mt*16 + quad*4 + r) * 34 + nt*16 + l15] = acc[mt][nt][r] * 0.125f;

    // ---- epilogue: lane = edge ----
    {
        long ge = e0 + lane;
        float tv[32];
#pragma unroll
        for (int u = 0; u < 32; u++) tv[u] = Ts[lane * 34 + u];
        int src = srcp[ge], pm = perm[ge];
        float4 eaq = ((const float4*)ea_in)[ge];
        float ea[4] = {eaq.x, eaq.y, eaq.z, eaq.w};
        const float4* xp = (const float4*)(xl + (long)src * 32);
        float ef[32];
#pragma unroll
        for (int g = 0; g < 8; g++) {
            float4 xq = xp[g];
            ef[4*g+0] = 0.5f * xq.x * tv[4*g+0];
            ef[4*g+1] = 0.5f * xq.y * tv[4*g+1];
            ef[4*g+2] = 0.5f * xq.z * tv[4*g+2];
            ef[4*g+3] = 0.5f * xq.w * tv[4*g+3];
        }
        uint4* efp = (uint4*)(ef_bf + (long)pm * 32);
#pragma unroll
        for (int g = 0; g < 4; g++) {
            uint4 wv;
            wv.x = f2us2(ef[8*g+0], ef[8*g+1]);
            wv.y = f2us2(ef[8*g+2], ef[8*g+3]);
            wv.z = f2us2(ef[8*g+4], ef[8*g+5]);
            wv.w = f2us2(ef[8*g+6], ef[8*g+7]);
            efp[g] = wv;
        }
        float eo[4] = {0.f, 0.f, 0.f, 0.f};
#pragma unroll
        for (int u = 0; u < 32; u++) {
            float efu = ef[u];
#pragma unroll
            for (int v = 0; v < 4; v++) {
                float p = efu * ea[v];
                const float* sw = sew + (u * 4 + v) * 4;
#pragma unroll
                for (int k = 0; k < 4; k++) eo[k] = fmaf(p, sw[k], eo[k]);
            }
        }
        constexpr float SCE_SCALE = 0.02209708691f;
        float4 o;
        o.x = ea[0] + eo[0]*SCE_SCALE; o.y = ea[1] + eo[1]*SCE_SCALE;
        o.z = ea[2] + eo[2]*SCE_SCALE; o.w = ea[3] + eo[3]*SCE_SCALE;
        ((float4*)ea_out)[ge] = o;
    }
}

// --------- gather + node post via MFMA + fused next-layer lin1 --------------
__global__ __launch_bounds__(256) void k_gpost_f(
        const int* __restrict__ off, const unsigned short* __restrict__ ef,
        const float* __restrict__ nf_cur, const float* __restrict__ nattr,
        const unsigned short* __restrict__ wnp_l,
        const unsigned short* __restrict__ wnp_nx,
        float* __restrict__ nf_next, float* __restrict__ out_nf,
        float* __restrict__ xl, int last) {
    __shared__ f32a Xs[64 * 33];
    __shared__ f32a As[64 * 33];
    __shared__ f32a Ys[64 * 9];
    const int t = threadIdx.x;
    const long n0 = (long)blockIdx.x * 64;
    stage_xy(nf_cur, nattr, n0, t, Xs, Ys);

    {   // gather: 8 lanes/node (even/odd rows), 2 node batches
        int slot = t >> 3, g = (t >> 2) & 1, l4 = t & 3;
#pragma unroll
        for (int batch = 0; batch < 2; batch++) {
            int nl = batch * 32 + slot;
            long n = n0 + nl;
            float v[8] = {0.f,0.f,0.f,0.f,0.f,0.f,0.f,0.f};
            if (n < NN) {
                int b = off[n] + g, en = off[n + 1];
                for (int r = b; r < en; r += 2) {
                    uint4 q = *(const uint4*)(ef + (long)r * 32 + l4 * 8);
                    v[0] += us2f(q.x & 0xFFFFu); v[1] += us2f(q.x >> 16);
                    v[2] += us2f(q.y & 0xFFFFu); v[3] += us2f(q.y >> 16);
                    v[4] += us2f(q.z & 0xFFFFu); v[5] += us2f(q.z >> 16);
                    v[6] += us2f(q.w & 0xFFFFu); v[7] += us2f(q.w >> 16);
                }
            }
#pragma unroll
            for (int i = 0; i < 8; i++) v[i] += __shfl_xor(v[i], 4);
            if (g == 0) {
#pragma unroll
                for (int i = 0; i < 8; i++)
                    As[nl * 33 + l4 * 8 + i] = v[i] * 0.25f;
            }
        }
    }
    __syncthreads();

    const int lane = t & 63, w = t >> 6;
    const int l15 = lane & 15, quad = lane >> 4;
    const int nb = w * 16;
    float y[8], xk[8], ak[8];
#pragma unroll
    for (int v = 0; v < 8; v++) y[v] = Ys[(nb + l15) * 9 + v];
#pragma unroll
    for (int kt = 0; kt < 8; kt++) {
        xk[kt] = Xs[(nb + l15) * 33 + kt * 4 + quad];
        ak[kt] = As[(nb + l15) * 33 + kt * 4 + quad];
    }
    f32x4 sc0, sc1, l20, l21, al;
    sc0[0]=0.f;sc0[1]=0.f;sc0[2]=0.f;sc0[3]=0.f;
    sc1 = sc0; l20 = sc0; l21 = sc0; al = sc0;
#pragma unroll
    for (int kt = 0; kt < 8; kt++) {
        float xv = xk[kt], av = ak[kt];
        short8 ax = mk_frag(f2us2(xv*y[0], xv*y[1]), f2us2(xv*y[2], xv*y[3]),
                            f2us2(xv*y[4], xv*y[5]), f2us2(xv*y[6], xv*y[7]));
        short8 ag = mk_frag(f2us2(av*y[0], av*y[1]), f2us2(av*y[2], av*y[3]),
                            f2us2(av*y[4], av*y[5]), f2us2(av*y[6], av*y[7]));
        const short8 b2 = *(const short8*)(wnp_l + ((2 * 8 + kt) * 512) + lane * 8);
        const short8 b3 = *(const short8*)(wnp_l + ((3 * 8 + kt) * 512) + lane * 8);
        const short8 b4 = *(const short8*)(wnp_l + ((4 * 8 + kt) * 512) + lane * 8);
        const short8 b5 = *(const short8*)(wnp_l + ((5 * 8 + kt) * 512) + lane * 8);
        const short8 b6 = *(const short8*)(wnp_l + ((6 * 8 + kt) * 512) + lane * 8);
        sc0 = __builtin_amdgcn_mfma_f32_16x16x32_bf16(ax, b2, sc0, 0, 0, 0);
        sc1 = __builtin_amdgcn_mfma_f32_16x16x32_bf16(ax, b3, sc1, 0, 0, 0);
        l20 = __builtin_amdgcn_mfma_f32_16x16x32_bf16(ag, b4, l20, 0, 0, 0);
        l21 = __builtin_amdgcn_mfma_f32_16x16x32_bf16(ag, b5, l21, 0, 0, 0);
        al  = __builtin_amdgcn_mfma_f32_16x16x32_bf16(ag, b6, al,  0, 0, 0);
    }
    float s0v[4], s1v[4];
#pragma unroll
    for (int r = 0; r < 4; r++) {
        float alpha = __shfl(al[r], quad * 16) * 0.0625f;
        long n = n0 + nb + quad * 4 + r;
        float o0 = sc0[r] * 0.0625f + alpha * (l20[r] * 0.0625f);
        float o1 = sc1[r] * 0.0625f + alpha * (l21[r] * 0.0625f);
        if (last) {
            if (n < NN) {
                out_nf[n * 32 + l15]      = o0;
                out_nf[n * 32 + 16 + l15] = o1;
            }
        } else {
            float v0 = __sinf(o0), v1 = __sinf(o1);
            s0v[r] = v0; s1v[r] = v1;
            if (n < NN) {
                nf_next[n * 32 + l15]      = v0;
                nf_next[n * 32 + 16 + l15] = v1;
            }
        }
    }
    if (last) return;

    // ---- fused next-layer lin1: bounce sin(out) through Xs, 16 MFMAs ----
    __syncthreads();             // Xs reads (xk) are long done; safe to reuse
#pragma unroll
    for (int r = 0; r < 4; r++) {
        Xs[(nb + quad * 4 + r) * 33 + l15]      = s0v[r];
        Xs[(nb + quad * 4 + r) * 33 + 16 + l15] = s1v[r];
    }
    __syncthreads();
    float xk2[8];
#pragma unroll
    for (int kt = 0; kt < 8; kt++) xk2[kt] = Xs[(nb + l15) * 33 + kt * 4 + quad];
    f32x4 a0, a1;
    a0[0]=0.f;a0[1]=0.f;a0[2]=0.f;a0[3]=0.f;
    a1 = a0;
#pragma unroll
    for (int kt = 0; kt < 8; kt++) {
        float xv = xk2[kt];
        short8 a = mk_frag(f2us2(xv*y[0], xv*y[1]), f2us2(xv*y[2], xv*y[3]),
                           f2us2(xv*y[4], xv*y[5]), f2us2(xv*y[6], xv*y[7]));
        const short8 b0 = *(const short8*)(wnp_nx + ((0 * 8 + kt) * 512) + lane * 8);
        const short8 b1 = *(const short8*)(wnp_nx + ((1 * 8 + kt) * 512) + lane * 8);
        a0 = __builtin_amdgcn_mfma_f32_16x16x32_bf16(a, b0, a0, 0, 0, 0);
        a1 = __builtin_amdgcn_mfma_f32_16x16x32_bf16(a, b1, a1, 0, 0, 0);
    }
#pragma unroll
    for (int r = 0; r < 4; r++) {
        long n = n0 + nb + quad * 4 + r;
        if (n < NN) {
            xl[n * 32 + l15]      = a0[r] * 0.0625f;
            xl[n * 32 + 16 + l15] = a1[r] * 0.0625f;
        }
    }
}

// ---------------------------------------------------------------------------
extern "C" void kernel_launch(void* const* d_in, const int* in_sizes, int n_in,
                              void* d_out, int out_size, void* d_ws, size_t ws_size,
                              hipStream_t stream) {
    int I_nf, I_na, I_esrc, I_edst, I_ea, I_esc, I_sc, I_l1, I_l2, I_al, I_se, I_f0, I_f1;
    if (in_sizes[0] == 1600000) {            // dict order
        I_nf=0; I_na=1; I_esrc=2; I_edst=3; I_ea=4; I_esc=5;
        I_sc=6; I_l1=7; I_l2=8; I_al=9; I_se=10; I_f0=11; I_f1=12;
    } else {                                  // sorted keys
        I_al=0; I_ea=1; I_edst=2; I_esc=3; I_esrc=4; I_f0=5; I_f1=6;
        I_l1=7; I_l2=8; I_na=9; I_nf=10; I_sc=11; I_se=12;
    }
    const float* nf_in = (const float*)d_in[I_nf];
    const float* na    = (const float*)d_in[I_na];
    const int*   esrc  = (const int*)d_in[I_esrc];
    const int*   edst  = (const int*)d_in[I_edst];
    const float* ea_in = (const float*)d_in[I_ea];
    const float* escl  = (const float*)d_in[I_esc];
    const float* w_sc  = (const float*)d_in[I_sc];
    const float* w_l1  = (const float*)d_in[I_l1];
    const float* w_l2  = (const float*)d_in[I_l2];
    const float* w_al  = (const float*)d_in[I_al];
    const float* w_se  = (const float*)d_in[I_se];
    const float* w_f0  = (const float*)d_in[I_f0];
    const float* w_f1  = (const float*)d_in[I_f1];

    float* ws = (float*)d_ws;
    float* out_nf = (float*)d_out;              // f32 [50000*32]
    float* out_ea = out_nf + (long)NN * 32;     // f32 [800000*4]

    unsigned short* w0p     = (unsigned short*)(ws + OFF_W0P);
    unsigned short* w2p     = (unsigned short*)(ws + OFF_W2P);
    unsigned short* wnp     = (unsigned short*)(ws + OFF_WNP);
    int*            csr_off = (int*)(ws + OFF_OFF);
    int*            csr_cur = (int*)(ws + OFF_CUR);
    int*            perm    = (int*)(ws + OFF_PERM);
    int*            bsum    = (int*)(ws + OFF_BSUM);
    unsigned short* ef_bf   = (unsigned short*)(ws + OFF_EF);

    hipMemsetAsync(csr_cur, 0, NN * sizeof(int), stream);
    k_hist<<<3125, 256, 0, stream>>>(edst, csr_cur, w_f0, w_f1,
                                     w_l1, w_sc, w_l2, w_al, w0p, w2p, wnp);
    k_scan1<<<SCAN_BLOCKS, 256, 0, stream>>>(csr_cur, bsum);
    k_scan2<<<1, 256, 0, stream>>>(bsum);
    k_scan3<<<SCAN_BLOCKS, 256, 0, stream>>>(csr_cur, bsum, csr_off, csr_cur);
    k_perm<<<3125, 256, 0, stream>>>(edst, csr_cur, perm);

    // layer 0 lin1 (only explicit npre; layer 1's is fused into gpost)
    k_npre_m<<<782, 256, 0, stream>>>(nf_in, na, wnp, out_nf /*xl*/);

    // layer 0
    k_edge_w<<<3125, 256, 0, stream>>>(escl, esrc, perm, ea_in, out_ea,
                                       out_nf /*xl*/, w0p, w2p, w_se, ef_bf);
    k_gpost_f<<<782, 256, 0, stream>>>(csr_off, ef_bf, nf_in, na,
                                       wnp, wnp + 28672,
                                       ws + OFF_NF /*nf_next*/, out_nf,
                                       out_nf /*xl for layer 1*/, 0);
    // layer 1
    k_edge_w<<<3125, 256, 0, stream>>>(escl, esrc, perm, out_ea, out_ea,
                                       out_nf /*xl*/, w0p + 2048,
                                       w2p + 8192, w_se + 512, ef_bf);
    k_gpost_f<<<782, 256, 0, stream>>>(csr_off, ef_bf, ws + OFF_NF, na,
                                       wnp + 28672, wnp /*unused*/,
                                       ws + OFF_NF /*unused*/, out_nf,
                                       out_nf /*unused*/, 1);
}